// Round 6
// baseline (1887.754 us; speedup 1.0000x reference)
//
#include <hip/hip_runtime.h>
#include <hip/hip_bf16.h>
#include <math.h>

#define B 16
#define NTOK 4096
#define DIM 256
#define DEPTH 4
#define HEADS 8
#define DH 32
#define INNER 256
#define MLPD 1024
#define EPS 1e-5f
#define CH 32            // attention n-chunks per batch
#define CHTOK (NTOK/CH)  // 128 tokens per chunk

typedef _Float16 half8 __attribute__((ext_vector_type(8)));
typedef _Float16 half4v __attribute__((ext_vector_type(4)));
typedef float f32x4 __attribute__((ext_vector_type(4)));

// gelu(v) = 0.5 v (1 + erf(v/sqrt2)); erf via Abramowitz-Stegun 7.1.26,
// |err| < 1.5e-7 absolute. ~13 VALU ops (1 v_exp, 1 v_rcp).
__device__ __forceinline__ float gelu_fast(float v) {
    const float z = fabsf(v) * 0.70710678118654752440f;
    const float t = __builtin_amdgcn_rcpf(1.f + 0.3275911f * z);
    const float poly = t*(0.254829592f + t*(-0.284496736f +
                      t*(1.421413741f + t*(-1.453152027f + t*1.061405429f))));
    const float e = __expf(-z*z);
    const float erfv = copysignf(1.f - poly * e, v);
    return 0.5f * v * (1.f + erfv);
}

// ---------------------------------------------------------------------------
// Pack fp32 weight [K][C] into fp16 MFMA-fragment-major layout.
__global__ __launch_bounds__(256) void pack_w(
        const float* __restrict__ in, _Float16* __restrict__ out, int K, int C)
{
    in  += (size_t)blockIdx.z * K * C;
    out += (size_t)blockIdx.z * K * C;
    __shared__ float t[32][65];
    const int tid = threadIdx.x;
    const int c0 = blockIdx.x * 64, k0 = blockIdx.y * 32;
    #pragma unroll
    for (int i = 0; i < 8; ++i) {
        int flat = tid + 256*i;
        int kk = flat >> 6, ccl = flat & 63;
        t[kk][ccl] = in[(size_t)(k0 + kk)*C + c0 + ccl];
    }
    __syncthreads();
    const int lane = tid & 63, ctl = tid >> 6;
    const int ccl = ctl*16 + (lane & 15);
    const int kb = (lane >> 4) * 8;
    half8 v;
    #pragma unroll
    for (int i = 0; i < 8; ++i) v[i] = (_Float16)t[kb + i][ccl];
    size_t off = ((size_t)((c0 >> 4) + ctl) * (K/32) + (k0 >> 5)) * 64 + lane;
    *((half8*)out + off) = v;
}

// ---------------------------------------------------------------------------
// K1: gather center token, q = sel@Wq (redundant per block), then
// qk[b][h][c] = ascale * sum_d Wk[c][h*32+d] * q[h*32+d].  grid (4, B).
__global__ __launch_bounds__(256) void qk2_kernel(
        const float* __restrict__ x, const int* __restrict__ pidx,
        const int* __restrict__ scale,
        const float* __restrict__ Wq, const float* __restrict__ Wk,
        float* __restrict__ qk)
{
    const int b = blockIdx.y;
    const int tid = threadIdx.x;
    const int wave = tid >> 6, lane = tid & 63;
    __shared__ float sel[DIM];
    __shared__ float qs[DIM];
    const int idx = pidx[b*2 + 0] * scale[1] + pidx[b*2 + 1];
    sel[tid] = x[(size_t)b*NTOK*DIM + (size_t)idx*DIM + tid];
    __syncthreads();
    float qacc = 0.f;
    #pragma unroll 4
    for (int c = 0; c < DIM; ++c) qacc += sel[c] * Wq[c*INNER + tid];
    qs[tid] = qacc;
    __syncthreads();
    const float ascale = 0.17677669529663687f; // 32^-0.5
    const float4 qv = *(const float4*)&qs[lane*4];
    #pragma unroll 4
    for (int i = 0; i < 16; ++i) {
        const int c = blockIdx.x*64 + wave*16 + i;
        const float4 w = *(const float4*)&Wk[(size_t)c*INNER + lane*4];
        float part = w.x*qv.x + w.y*qv.y + w.z*qv.z + w.w*qv.w;
        part += __shfl_xor(part, 1);
        part += __shfl_xor(part, 2);
        part += __shfl_xor(part, 4);
        if ((lane & 7) == 0)
            qk[(b*HEADS + (lane >> 3))*DIM + c] = part * ascale;
    }
}

// ---------------------------------------------------------------------------
// K2: fused dots+softmax+xa, flash-style online softmax per chunk.
// grid (CH, B), 256 threads. Each block streams CHTOK tokens once, keeps
// per-head running (m,s) in LDS and per-(h, c=tid) partial xa in registers.
__global__ __launch_bounds__(256) void attn_pass(
        const float* __restrict__ x, const float* __restrict__ qkg,
        float* __restrict__ pxa, float* __restrict__ pm, float* __restrict__ ps)
{
    const int b = blockIdx.y, ch = blockIdx.x;
    const int tid = threadIdx.x;
    __shared__ float qks[HEADS][260];
    __shared__ float xs[32][260];
    __shared__ float dotss[32][8];      // dots, then reused as weights
    __shared__ float mrun[8], srun[8], mnew_s[8], escale_s[8];

    const float4* qg = (const float4*)(qkg + (size_t)b*HEADS*DIM);
    #pragma unroll
    for (int i = 0; i < 2; ++i) {
        int flat = tid + 256*i;
        int h = flat >> 6, c4 = flat & 63;
        *(float4*)&qks[h][c4*4] = qg[flat];
    }
    if (tid < 8) { mrun[tid] = -3.4e38f; srun[tid] = 0.f; }
    float acc[8];
    #pragma unroll
    for (int h = 0; h < 8; ++h) acc[h] = 0.f;
    __syncthreads();

    for (int st = 0; st < CHTOK/32; ++st) {
        const size_t n0 = (size_t)ch*CHTOK + st*32;
        // stage 32 token rows (xs was fully consumed before loop or at end)
        const float4* xg = (const float4*)(x + ((size_t)b*NTOK + n0)*DIM);
        #pragma unroll
        for (int i = 0; i < 8; ++i) {
            int flat = tid + 256*i;
            int r = flat >> 6, c4 = flat & 63;
            *(float4*)&xs[r][c4*4] = xg[flat];
        }
        __syncthreads();
        // dots: thread = (tok, h)
        {
            const int tok = tid >> 3, h = tid & 7;
            float d = 0.f;
            #pragma unroll 8
            for (int i = 0; i < 64; ++i) {
                float4 xv = *(const float4*)&xs[tok][i*4];
                float4 qv = *(const float4*)&qks[h][i*4];
                d += xv.x*qv.x + xv.y*qv.y + xv.z*qv.z + xv.w*qv.w;
            }
            dotss[tok][h] = d;
        }
        __syncthreads();
        // per-head tile max + rescale factor (8 stat threads)
        if (tid < 8) {
            float tm = -3.4e38f;
            #pragma unroll
            for (int n = 0; n < 32; ++n) tm = fmaxf(tm, dotss[n][tid]);
            const float mo = mrun[tid];
            const float mn = fmaxf(mo, tm);
            mnew_s[tid] = mn;
            escale_s[tid] = __expf(mo - mn);
        }
        __syncthreads();
        // weights in place: thread = (tok, h)
        {
            const int tok = tid >> 3, h = tid & 7;
            dotss[tok][h] = __expf(dotss[tok][h] - mnew_s[h]);
        }
        __syncthreads();
        // accumulate: thread owns column c = tid for all heads
        #pragma unroll
        for (int h = 0; h < 8; ++h) acc[h] *= escale_s[h];
        #pragma unroll 4
        for (int n = 0; n < 32; ++n) {
            const float xv = xs[n][tid];
            const float4 w0 = *(const float4*)&dotss[n][0];
            const float4 w1 = *(const float4*)&dotss[n][4];
            acc[0] += w0.x*xv; acc[1] += w0.y*xv;
            acc[2] += w0.z*xv; acc[3] += w0.w*xv;
            acc[4] += w1.x*xv; acc[5] += w1.y*xv;
            acc[6] += w1.z*xv; acc[7] += w1.w*xv;
        }
        // running sum update (stat threads; dotss stable until next dots)
        if (tid < 8) {
            float ts = 0.f;
            #pragma unroll
            for (int n = 0; n < 32; ++n) ts += dotss[n][tid];
            srun[tid] = srun[tid]*escale_s[tid] + ts;
            mrun[tid] = mnew_s[tid];
        }
        __syncthreads();   // xs/dotss free for next subtile
    }
    // write partials
    const size_t base = ((size_t)b*CH + ch)*HEADS;
    #pragma unroll
    for (int h = 0; h < 8; ++h)
        pxa[(base + h)*DIM + tid] = acc[h];
    if (tid < 8) { pm[base + tid] = mrun[tid]; ps[base + tid] = srun[tid]; }
}

// ---------------------------------------------------------------------------
// K3: combine chunk partials -> xa, then vo = xa@Wv (per head),
// out = vo@Wo + bo, x[b,idx] += out.  grid B, 256 threads.
__global__ __launch_bounds__(256) void attn_fin(
        const float* __restrict__ pxa, const float* __restrict__ pm,
        const float* __restrict__ ps,
        const float* __restrict__ Wv, const float* __restrict__ Wo,
        const float* __restrict__ bo, const int* __restrict__ pidx,
        const int* __restrict__ scale, float* __restrict__ x)
{
    const int b = blockIdx.x;
    const int tid = threadIdx.x;
    __shared__ float xa_s[HEADS*DIM];
    __shared__ float vs[INNER];

    #pragma unroll
    for (int h = 0; h < 8; ++h) {
        float gm = -3.4e38f;
        for (int ch = 0; ch < CH; ++ch)
            gm = fmaxf(gm, pm[((size_t)b*CH + ch)*HEADS + h]);
        float gs = 0.f;
        for (int ch = 0; ch < CH; ++ch) {
            const size_t o = ((size_t)b*CH + ch)*HEADS + h;
            gs += __expf(pm[o] - gm) * ps[o];
        }
        float v = 0.f;
        for (int ch = 0; ch < CH; ++ch) {
            const size_t o = ((size_t)b*CH + ch)*HEADS + h;
            v += __expf(pm[o] - gm) * pxa[o*DIM + tid];
        }
        xa_s[h*DIM + tid] = v / gs;
    }
    __syncthreads();
    const int h2 = tid >> 5;
    float a = 0.f;
    #pragma unroll 4
    for (int c = 0; c < DIM; ++c) a += xa_s[h2*DIM + c] * Wv[c*INNER + tid];
    vs[tid] = a;
    __syncthreads();
    float o = bo[tid];
    #pragma unroll 4
    for (int i = 0; i < INNER; ++i) o += vs[i] * Wo[i*DIM + tid];
    const int idx = pidx[b*2 + 0] * scale[1] + pidx[b*2 + 1];
    x[(size_t)b*NTOK*DIM + (size_t)idx*DIM + tid] += o;
}

// ---------------------------------------------------------------------------
// K4: fused FFN, fp16 MFMA, 64-token tile, 4 waves, 48 KB LDS (3 blocks/CU).
// Each 256-wide MLP chunk processed in two 128-wide output halves through a
// single 16 KB hsT buffer.
__global__ __launch_bounds__(256, 3) void ffn_mfma(
        float* __restrict__ x,
        const float* __restrict__ g, const float* __restrict__ bvec,
        const _Float16* __restrict__ W1F, const float* __restrict__ b1,
        const _Float16* __restrict__ W2F, const float* __restrict__ b2)
{
    __shared__ _Float16 xs[64*256];   // [t][k], swizzled, 32 KB
    __shared__ _Float16 hsT[64*128];  // [t][c-half], swizzled, 16 KB
    const int tid = threadIdx.x;
    const size_t row0 = (size_t)blockIdx.x * 64;

    // ---- LN (fp32) -> fp16 -> xs
    {
        const int r = tid >> 2, p = tid & 3;
        const float4* xg = (const float4*)(x + (row0 + r)*DIM) + p*16;
        float4 v[16];
        float s = 0.f, s2 = 0.f;
        #pragma unroll
        for (int i = 0; i < 16; ++i) {
            v[i] = xg[i];
            s  += v[i].x + v[i].y + v[i].z + v[i].w;
            s2 += v[i].x*v[i].x + v[i].y*v[i].y + v[i].z*v[i].z + v[i].w*v[i].w;
        }
        s  += __shfl_xor(s, 1);  s  += __shfl_xor(s, 2);
        s2 += __shfl_xor(s2, 1); s2 += __shfl_xor(s2, 2);
        const float mean = s * (1.f/DIM);
        const float rstd = rsqrtf(s2*(1.f/DIM) - mean*mean + EPS);
        #pragma unroll
        for (int q = 0; q < 8; ++q) {
            const int c8 = p*64 + q*8;
            const float4 ga = *(const float4*)&g[c8];
            const float4 gb = *(const float4*)&g[c8+4];
            const float4 ba = *(const float4*)&bvec[c8];
            const float4 bb = *(const float4*)&bvec[c8+4];
            const float4 a = v[2*q], d = v[2*q+1];
            half8 hh;
            hh[0] = (_Float16)((a.x-mean)*rstd*ga.x + ba.x);
            hh[1] = (_Float16)((a.y-mean)*rstd*ga.y + ba.y);
            hh[2] = (_Float16)((a.z-mean)*rstd*ga.z + ba.z);
            hh[3] = (_Float16)((a.w-mean)*rstd*ga.w + ba.w);
            hh[4] = (_Float16)((d.x-mean)*rstd*gb.x + bb.x);
            hh[5] = (_Float16)((d.y-mean)*rstd*gb.y + bb.y);
            hh[6] = (_Float16)((d.z-mean)*rstd*gb.z + bb.z);
            hh[7] = (_Float16)((d.w-mean)*rstd*gb.w + bb.w);
            int byte = r*512 + c8*2;
            byte ^= (r & 7) << 4;
            *(half8*)((char*)xs + byte) = hh;
        }
    }
    __syncthreads();

    const int wave = tid >> 6, lane = tid & 63;
    const int lr = lane & 15, lhi = lane >> 4;

    f32x4 acc2[4][4];
    #pragma unroll
    for (int m = 0; m < 4; ++m)
        #pragma unroll
        for (int n = 0; n < 4; ++n) acc2[m][n] = (f32x4)0.f;

    half8 aA[4], aB[4], bA[4], bB[4];

    for (int cc = 0; cc < 4; ++cc) {
        #pragma unroll
        for (int half = 0; half < 2; ++half) {
            // GEMM1 output c-tiles: ct1 = cc*16 + half*8 + m*4 + wave, m=0..1
            auto ldA1 = [&](int ks, half8* a) {
                #pragma unroll
                for (int m = 0; m < 2; ++m)
                    a[m] = *((const half8*)W1F +
                        (size_t)((cc*16 + half*8 + m*4 + wave)*8 + ks)*64 + lane);
            };
            auto ldBx = [&](int ks, half8* bf) {
                #pragma unroll
                for (int n = 0; n < 4; ++n) {
                    int byte = (n*16 + lr)*512 + (ks*32 + lhi*8)*2;
                    byte ^= (lr & 7) << 4;
                    bf[n] = *(const half8*)((const char*)xs + byte);
                }
            };
            auto mm1 = [&](f32x4 (&acc)[2][4], half8* a, half8* bf) {
                __builtin_amdgcn_s_setprio(1);
                #pragma unroll
                for (int m = 0; m < 2; ++m)
                    #pragma unroll
                    for (int n = 0; n < 4; ++n)
                        acc[m][n] = __builtin_amdgcn_mfma_f32_16x16x32_f16(
                            a[m], bf[n], acc[m][n], 0, 0, 0);
                __builtin_amdgcn_s_setprio(0);
            };
            f32x4 acc1[2][4];
            #pragma unroll
            for (int m = 0; m < 2; ++m)
                #pragma unroll
                for (int n = 0; n < 4; ++n) acc1[m][n] = (f32x4)0.f;
            ldA1(0, aA); ldBx(0, bA);
            #pragma unroll
            for (int kp = 0; kp < 4; ++kp) {
                ldA1(2*kp+1, aB); ldBx(2*kp+1, bB);
                mm1(acc1, aA, bA);
                if (kp < 3) { ldA1(2*kp+2, aA); ldBx(2*kp+2, bA); }
                mm1(acc1, aB, bB);
            }
            // prefetch GEMM2 first A + b1 before barrier
            f32x4 b1r[2];
            #pragma unroll
            for (int m = 0; m < 2; ++m)
                b1r[m] = *(const f32x4*)(b1 + cc*256 + half*128 +
                                         (m*4 + wave)*16 + lhi*4);
            auto ldA2 = [&](int ks2, half8* a) {
                const int kb = cc*8 + half*4 + ks2;
                #pragma unroll
                for (int m = 0; m < 4; ++m)
                    a[m] = *((const half8*)W2F +
                        (size_t)((wave*4 + m)*32 + kb)*64 + lane);
            };
            ldA2(0, aA);
            __syncthreads();   // prev GEMM2 done reading hsT
            // bias + GELU -> hsT (half, swizzled)
            #pragma unroll
            for (int m = 0; m < 2; ++m) {
                const int c_local = (m*4 + wave)*16 + lhi*4;
                #pragma unroll
                for (int n = 0; n < 4; ++n) {
                    const int t = n*16 + lr;
                    half4v hv;
                    hv[0] = (_Float16)gelu_fast(acc1[m][n][0] + b1r[m][0]);
                    hv[1] = (_Float16)gelu_fast(acc1[m][n][1] + b1r[m][1]);
                    hv[2] = (_Float16)gelu_fast(acc1[m][n][2] + b1r[m][2]);
                    hv[3] = (_Float16)gelu_fast(acc1[m][n][3] + b1r[m][3]);
                    int byte = t*256 + c_local*2;
                    byte ^= (t & 7) << 4;
                    *(half4v*)((char*)hsT + byte) = hv;
                }
            }
            __syncthreads();   // hsT ready
            auto ldBh = [&](int ks2, half8* bf) {
                #pragma unroll
                for (int n = 0; n < 4; ++n) {
                    const int t = n*16 + lr;
                    int byte = t*256 + (ks2*32 + lhi*8)*2;
                    byte ^= (t & 7) << 4;
                    bf[n] = *(const half8*)((const char*)hsT + byte);
                }
            };
            auto mm2 = [&](half8* a, half8* bf) {
                __builtin_amdgcn_s_setprio(1);
                #pragma unroll
                for (int m = 0; m < 4; ++m)
                    #pragma unroll
                    for (int n = 0; n < 4; ++n)
                        acc2[m][n] = __builtin_amdgcn_mfma_f32_16x16x32_f16(
                            a[m], bf[n], acc2[m][n], 0, 0, 0);
                __builtin_amdgcn_s_setprio(0);
            };
            // GEMM2 over this half's K=128 (4 ks), 2-deep pipeline
            ldBh(0, bA);
            ldA2(1, aB); ldBh(1, bB);
            mm2(aA, bA);
            ldA2(2, aA); ldBh(2, bA);
            mm2(aB, bB);
            ldA2(3, aB); ldBh(3, bB);
            mm2(aA, bA);
            mm2(aB, bB);
        }
    }
    // ---- epilogue: Y^T + b2 + residual -> x
    #pragma unroll
    for (int m = 0; m < 4; ++m) {
        const int c0 = wave*64 + m*16 + lhi*4;
        const f32x4 b2v = *(const f32x4*)(b2 + c0);
        #pragma unroll
        for (int n = 0; n < 4; ++n) {
            const int t = n*16 + lr;
            float* xp = x + (row0 + t)*DIM + c0;
            float4 r = *(const float4*)xp;
            r.x += acc2[m][n][0] + b2v[0];
            r.y += acc2[m][n][1] + b2v[1];
            r.z += acc2[m][n][2] + b2v[2];
            r.w += acc2[m][n][3] + b2v[3];
            *(float4*)xp = r;
        }
    }
}

// ---------------------------------------------------------------------------
// K5: final layernorm
__global__ __launch_bounds__(256) void final_ln_kernel(
        const float* __restrict__ x, const float* __restrict__ g,
        const float* __restrict__ bvec, float* __restrict__ out)
{
    const int tid = threadIdx.x;
    const size_t row = (size_t)blockIdx.x*32 + (tid >> 3);
    const int p = tid & 7;
    const float4* xr = (const float4*)(x + row*DIM);
    float4 v[8];
    float s = 0.f, s2 = 0.f;
    #pragma unroll
    for (int i = 0; i < 8; ++i) {
        v[i] = xr[p + 8*i];
        s  += v[i].x + v[i].y + v[i].z + v[i].w;
        s2 += v[i].x*v[i].x + v[i].y*v[i].y + v[i].z*v[i].z + v[i].w*v[i].w;
    }
    #pragma unroll
    for (int o = 1; o < 8; o <<= 1) { s += __shfl_xor(s, o); s2 += __shfl_xor(s2, o); }
    const float mean = s * (1.f/DIM);
    const float rstd = rsqrtf(s2*(1.f/DIM) - mean*mean + EPS);
    float4* og = (float4*)(out + row*DIM);
    #pragma unroll
    for (int i = 0; i < 8; ++i) {
        const int c4 = (p + 8*i)*4;
        const float4 gg = *(const float4*)&g[c4];
        const float4 bb = *(const float4*)&bvec[c4];
        float4 o_;
        o_.x = (v[i].x - mean)*rstd*gg.x + bb.x;
        o_.y = (v[i].y - mean)*rstd*gg.y + bb.y;
        o_.z = (v[i].z - mean)*rstd*gg.z + bb.z;
        o_.w = (v[i].w - mean)*rstd*gg.w + bb.w;
        og[p + 8*i] = o_;
    }
}

// ---------------------------------------------------------------------------
extern "C" void kernel_launch(void* const* d_in, const int* in_sizes, int n_in,
                              void* d_out, int out_size, void* d_ws, size_t ws_size,
                              hipStream_t stream)
{
    const float* x_in  = (const float*)d_in[0];
    const int*   pidx  = (const int*)d_in[1];
    const int*   scale = (const int*)d_in[3];
    const float* Wq    = (const float*)d_in[4];
    const float* Wk    = (const float*)d_in[5];
    const float* Wv    = (const float*)d_in[6];
    const float* Wo    = (const float*)d_in[7];
    const float* bo    = (const float*)d_in[8];
    const float* ln_g  = (const float*)d_in[9];
    const float* ln_b  = (const float*)d_in[10];
    const float* W1    = (const float*)d_in[11];
    const float* b1    = (const float*)d_in[12];
    const float* W2    = (const float*)d_in[13];
    const float* b2    = (const float*)d_in[14];
    const float* lnf_g = (const float*)d_in[15];
    const float* lnf_b = (const float*)d_in[16];

    float* xbuf = (float*)d_out;                         // x lives in d_out
    float* qk   = (float*)d_ws;                          // B*H*DIM
    float* pxa  = qk + (size_t)B*HEADS*DIM;              // B*CH*H*DIM
    float* pm   = pxa + (size_t)B*CH*HEADS*DIM;          // B*CH*H
    float* ps   = pm + (size_t)B*CH*HEADS;               // B*CH*H
    _Float16* W1F = (_Float16*)(ps + (size_t)B*CH*HEADS);   // DEPTH*DIM*MLPD
    _Float16* W2F = W1F + (size_t)DEPTH*DIM*MLPD;           // DEPTH*MLPD*DIM

    pack_w<<<dim3(MLPD/64, DIM/32, DEPTH), 256, 0, stream>>>(W1, W1F, DIM, MLPD);
    pack_w<<<dim3(DIM/64, MLPD/32, DEPTH), 256, 0, stream>>>(W2, W2F, MLPD, DIM);

    hipMemcpyAsync(xbuf, x_in, (size_t)B*NTOK*DIM*sizeof(float),
                   hipMemcpyDeviceToDevice, stream);

    for (int l = 0; l < DEPTH; ++l) {
        qk2_kernel<<<dim3(4, B), 256, 0, stream>>>(
            xbuf, pidx, scale,
            Wq + (size_t)l*DIM*INNER, Wk + (size_t)l*DIM*INNER, qk);
        attn_pass<<<dim3(CH, B), 256, 0, stream>>>(xbuf, qk, pxa, pm, ps);
        attn_fin<<<B, 256, 0, stream>>>(
            pxa, pm, ps, Wv + (size_t)l*DIM*INNER, Wo + (size_t)l*INNER*DIM,
            bo + (size_t)l*DIM, pidx, scale, xbuf);
        ffn_mfma<<<(B*NTOK)/64, 256, 0, stream>>>(
            xbuf, ln_g + (size_t)l*DIM, ln_b + (size_t)l*DIM,
            W1F + (size_t)l*DIM*MLPD, b1 + (size_t)l*MLPD,
            W2F + (size_t)l*MLPD*DIM, b2 + (size_t)l*DIM);
    }
    final_ln_kernel<<<(B*NTOK)/32, 256, 0, stream>>>(xbuf, lnf_g, lnf_b, xbuf);
}

// Round 8
// 1453.179 us; speedup vs baseline: 1.2991x; 1.2991x over previous
//
#include <hip/hip_runtime.h>
#include <hip/hip_bf16.h>
#include <math.h>

#define B 16
#define NTOK 4096
#define DIM 256
#define DEPTH 4
#define HEADS 8
#define DH 32
#define INNER 256
#define MLPD 1024
#define EPS 1e-5f
#define CH 32            // attention n-chunks per batch
#define CHTOK (NTOK/CH)  // 128 tokens per chunk

typedef _Float16 half8 __attribute__((ext_vector_type(8)));
typedef _Float16 half4v __attribute__((ext_vector_type(4)));
typedef float f32x4 __attribute__((ext_vector_type(4)));

// gelu(v) = 0.5 v (1 + erf(v/sqrt2)); erf via Abramowitz-Stegun 7.1.26,
// |err| < 1.5e-7 absolute. ~13 VALU ops (1 v_exp, 1 v_rcp).
__device__ __forceinline__ float gelu_fast(float v) {
    const float z = fabsf(v) * 0.70710678118654752440f;
    const float t = __builtin_amdgcn_rcpf(1.f + 0.3275911f * z);
    const float poly = t*(0.254829592f + t*(-0.284496736f +
                      t*(1.421413741f + t*(-1.453152027f + t*1.061405429f))));
    const float e = __expf(-z*z);
    const float erfv = copysignf(1.f - poly * e, v);
    return 0.5f * v * (1.f + erfv);
}

// ---------------------------------------------------------------------------
// Pack fp32 weight [K][C] into fp16 MFMA-fragment-major layout.
__global__ __launch_bounds__(256) void pack_w(
        const float* __restrict__ in, _Float16* __restrict__ out, int K, int C)
{
    in  += (size_t)blockIdx.z * K * C;
    out += (size_t)blockIdx.z * K * C;
    __shared__ float t[32][65];
    const int tid = threadIdx.x;
    const int c0 = blockIdx.x * 64, k0 = blockIdx.y * 32;
    #pragma unroll
    for (int i = 0; i < 8; ++i) {
        int flat = tid + 256*i;
        int kk = flat >> 6, ccl = flat & 63;
        t[kk][ccl] = in[(size_t)(k0 + kk)*C + c0 + ccl];
    }
    __syncthreads();
    const int lane = tid & 63, ctl = tid >> 6;
    const int ccl = ctl*16 + (lane & 15);
    const int kb = (lane >> 4) * 8;
    half8 v;
    #pragma unroll
    for (int i = 0; i < 8; ++i) v[i] = (_Float16)t[kb + i][ccl];
    size_t off = ((size_t)((c0 >> 4) + ctl) * (K/32) + (k0 >> 5)) * 64 + lane;
    *((half8*)out + off) = v;
}

// ---------------------------------------------------------------------------
// K1: gather center token, q = sel@Wq (redundant per block), then
// qk[b][h][c] = ascale * sum_d Wk[c][h*32+d] * q[h*32+d].  grid (4, B).
__global__ __launch_bounds__(256) void qk2_kernel(
        const float* __restrict__ x, const int* __restrict__ pidx,
        const int* __restrict__ scale,
        const float* __restrict__ Wq, const float* __restrict__ Wk,
        float* __restrict__ qk)
{
    const int b = blockIdx.y;
    const int tid = threadIdx.x;
    const int wave = tid >> 6, lane = tid & 63;
    __shared__ float sel[DIM];
    __shared__ float qs[DIM];
    const int idx = pidx[b*2 + 0] * scale[1] + pidx[b*2 + 1];
    sel[tid] = x[(size_t)b*NTOK*DIM + (size_t)idx*DIM + tid];
    __syncthreads();
    float qacc = 0.f;
    #pragma unroll 4
    for (int c = 0; c < DIM; ++c) qacc += sel[c] * Wq[c*INNER + tid];
    qs[tid] = qacc;
    __syncthreads();
    const float ascale = 0.17677669529663687f; // 32^-0.5
    const float4 qv = *(const float4*)&qs[lane*4];
    #pragma unroll 4
    for (int i = 0; i < 16; ++i) {
        const int c = blockIdx.x*64 + wave*16 + i;
        const float4 w = *(const float4*)&Wk[(size_t)c*INNER + lane*4];
        float part = w.x*qv.x + w.y*qv.y + w.z*qv.z + w.w*qv.w;
        part += __shfl_xor(part, 1);
        part += __shfl_xor(part, 2);
        part += __shfl_xor(part, 4);
        if ((lane & 7) == 0)
            qk[(b*HEADS + (lane >> 3))*DIM + c] = part * ascale;
    }
}

// ---------------------------------------------------------------------------
// K2: fused dots+softmax+xa, flash-style online softmax per chunk.
// grid (CH, B), 256 threads.
__global__ __launch_bounds__(256) void attn_pass(
        const float* __restrict__ x, const float* __restrict__ qkg,
        float* __restrict__ pxa, float* __restrict__ pm, float* __restrict__ ps)
{
    const int b = blockIdx.y, ch = blockIdx.x;
    const int tid = threadIdx.x;
    __shared__ float qks[HEADS][260];
    __shared__ float xs[32][260];
    __shared__ float dotss[32][8];      // dots, then reused as weights
    __shared__ float mrun[8], srun[8], mnew_s[8], escale_s[8];

    const float4* qg = (const float4*)(qkg + (size_t)b*HEADS*DIM);
    #pragma unroll
    for (int i = 0; i < 2; ++i) {
        int flat = tid + 256*i;
        int h = flat >> 6, c4 = flat & 63;
        *(float4*)&qks[h][c4*4] = qg[flat];
    }
    if (tid < 8) { mrun[tid] = -3.4e38f; srun[tid] = 0.f; }
    float acc[8];
    #pragma unroll
    for (int h = 0; h < 8; ++h) acc[h] = 0.f;
    __syncthreads();

    for (int st = 0; st < CHTOK/32; ++st) {
        const size_t n0 = (size_t)ch*CHTOK + st*32;
        const float4* xg = (const float4*)(x + ((size_t)b*NTOK + n0)*DIM);
        #pragma unroll
        for (int i = 0; i < 8; ++i) {
            int flat = tid + 256*i;
            int r = flat >> 6, c4 = flat & 63;
            *(float4*)&xs[r][c4*4] = xg[flat];
        }
        __syncthreads();
        // dots: thread = (tok, h)
        {
            const int tok = tid >> 3, h = tid & 7;
            float d = 0.f;
            #pragma unroll 8
            for (int i = 0; i < 64; ++i) {
                float4 xv = *(const float4*)&xs[tok][i*4];
                float4 qv = *(const float4*)&qks[h][i*4];
                d += xv.x*qv.x + xv.y*qv.y + xv.z*qv.z + xv.w*qv.w;
            }
            dotss[tok][h] = d;
        }
        __syncthreads();
        if (tid < 8) {
            float tm = -3.4e38f;
            #pragma unroll
            for (int n = 0; n < 32; ++n) tm = fmaxf(tm, dotss[n][tid]);
            const float mo = mrun[tid];
            const float mn = fmaxf(mo, tm);
            mnew_s[tid] = mn;
            escale_s[tid] = __expf(mo - mn);
        }
        __syncthreads();
        {
            const int tok = tid >> 3, h = tid & 7;
            dotss[tok][h] = __expf(dotss[tok][h] - mnew_s[h]);
        }
        __syncthreads();
        #pragma unroll
        for (int h = 0; h < 8; ++h) acc[h] *= escale_s[h];
        #pragma unroll 4
        for (int n = 0; n < 32; ++n) {
            const float xv = xs[n][tid];
            const float4 w0 = *(const float4*)&dotss[n][0];
            const float4 w1 = *(const float4*)&dotss[n][4];
            acc[0] += w0.x*xv; acc[1] += w0.y*xv;
            acc[2] += w0.z*xv; acc[3] += w0.w*xv;
            acc[4] += w1.x*xv; acc[5] += w1.y*xv;
            acc[6] += w1.z*xv; acc[7] += w1.w*xv;
        }
        if (tid < 8) {
            float ts = 0.f;
            #pragma unroll
            for (int n = 0; n < 32; ++n) ts += dotss[n][tid];
            srun[tid] = srun[tid]*escale_s[tid] + ts;
            mrun[tid] = mnew_s[tid];
        }
        __syncthreads();
    }
    const size_t base = ((size_t)b*CH + ch)*HEADS;
    #pragma unroll
    for (int h = 0; h < 8; ++h)
        pxa[(base + h)*DIM + tid] = acc[h];
    if (tid < 8) { pm[base + tid] = mrun[tid]; ps[base + tid] = srun[tid]; }
}

// ---------------------------------------------------------------------------
// K3: combine chunk partials -> xa, then vo = xa@Wv (per head),
// out = vo@Wo + bo, x[b,idx] += out.  grid B, 256 threads.
__global__ __launch_bounds__(256) void attn_fin(
        const float* __restrict__ pxa, const float* __restrict__ pm,
        const float* __restrict__ ps,
        const float* __restrict__ Wv, const float* __restrict__ Wo,
        const float* __restrict__ bo, const int* __restrict__ pidx,
        const int* __restrict__ scale, float* __restrict__ x)
{
    const int b = blockIdx.x;
    const int tid = threadIdx.x;
    __shared__ float xa_s[HEADS*DIM];
    __shared__ float vs[INNER];

    #pragma unroll
    for (int h = 0; h < 8; ++h) {
        float gm = -3.4e38f;
        for (int ch = 0; ch < CH; ++ch)
            gm = fmaxf(gm, pm[((size_t)b*CH + ch)*HEADS + h]);
        float gs = 0.f;
        for (int ch = 0; ch < CH; ++ch) {
            const size_t o = ((size_t)b*CH + ch)*HEADS + h;
            gs += __expf(pm[o] - gm) * ps[o];
        }
        float v = 0.f;
        for (int ch = 0; ch < CH; ++ch) {
            const size_t o = ((size_t)b*CH + ch)*HEADS + h;
            v += __expf(pm[o] - gm) * pxa[o*DIM + tid];
        }
        xa_s[h*DIM + tid] = v / gs;
    }
    __syncthreads();
    const int h2 = tid >> 5;
    float a = 0.f;
    #pragma unroll 4
    for (int c = 0; c < DIM; ++c) a += xa_s[h2*DIM + c] * Wv[c*INNER + tid];
    vs[tid] = a;
    __syncthreads();
    float o = bo[tid];
    #pragma unroll 4
    for (int i = 0; i < INNER; ++i) o += vs[i] * Wo[i*DIM + tid];
    const int idx = pidx[b*2 + 0] * scale[1] + pidx[b*2 + 1];
    x[(size_t)b*NTOK*DIM + (size_t)idx*DIM + tid] += o;
}

// ---------------------------------------------------------------------------
// K4: fused FFN, fp16 MFMA, 64-token tile, 4 waves, 2-deep register pipeline.
// ROUND-3 MEASURED CONFIG: launch_bounds(256,2), 64 KB LDS, VGPR 128 — 158 µs.
// (round-6 (256,3)/48KB variant spilled: VGPR 84 < 64-reg accumulator floor
//  -> +230 MB scratch traffic/dispatch. Do not re-tighten without reg math.)
__global__ __launch_bounds__(256, 2) void ffn_mfma(
        float* __restrict__ x,
        const float* __restrict__ g, const float* __restrict__ bvec,
        const _Float16* __restrict__ W1F, const float* __restrict__ b1,
        const _Float16* __restrict__ W2F, const float* __restrict__ b2)
{
    __shared__ _Float16 xs[64*256];   // [t][k], swizzled
    __shared__ _Float16 hsT[64*256];  // [t][chunk-c], swizzled
    const int tid = threadIdx.x;
    const size_t row0 = (size_t)blockIdx.x * 64;

    // ---- phase 1: LN (fp32) -> fp16 -> xs
    {
        const int r = tid >> 2, p = tid & 3;
        const float4* xg = (const float4*)(x + (row0 + r)*DIM) + p*16;
        float4 v[16];
        float s = 0.f, s2 = 0.f;
        #pragma unroll
        for (int i = 0; i < 16; ++i) {
            v[i] = xg[i];
            s  += v[i].x + v[i].y + v[i].z + v[i].w;
            s2 += v[i].x*v[i].x + v[i].y*v[i].y + v[i].z*v[i].z + v[i].w*v[i].w;
        }
        s  += __shfl_xor(s, 1);  s  += __shfl_xor(s, 2);
        s2 += __shfl_xor(s2, 1); s2 += __shfl_xor(s2, 2);
        const float mean = s * (1.f/DIM);
        const float rstd = rsqrtf(s2*(1.f/DIM) - mean*mean + EPS);
        #pragma unroll
        for (int q = 0; q < 8; ++q) {
            const int c8 = p*64 + q*8;
            const float4 ga = *(const float4*)&g[c8];
            const float4 gb = *(const float4*)&g[c8+4];
            const float4 ba = *(const float4*)&bvec[c8];
            const float4 bb = *(const float4*)&bvec[c8+4];
            const float4 a = v[2*q], d = v[2*q+1];
            half8 hh;
            hh[0] = (_Float16)((a.x-mean)*rstd*ga.x + ba.x);
            hh[1] = (_Float16)((a.y-mean)*rstd*ga.y + ba.y);
            hh[2] = (_Float16)((a.z-mean)*rstd*ga.z + ba.z);
            hh[3] = (_Float16)((a.w-mean)*rstd*ga.w + ba.w);
            hh[4] = (_Float16)((d.x-mean)*rstd*gb.x + bb.x);
            hh[5] = (_Float16)((d.y-mean)*rstd*gb.y + bb.y);
            hh[6] = (_Float16)((d.z-mean)*rstd*gb.z + bb.z);
            hh[7] = (_Float16)((d.w-mean)*rstd*gb.w + bb.w);
            int byte = r*512 + c8*2;
            byte ^= (r & 7) << 4;
            *(half8*)((char*)xs + byte) = hh;
        }
    }
    __syncthreads();

    const int wave = tid >> 6, lane = tid & 63;
    const int lr = lane & 15, lhi = lane >> 4;

    f32x4 acc2[4][4];
    #pragma unroll
    for (int m = 0; m < 4; ++m)
        #pragma unroll
        for (int n = 0; n < 4; ++n) acc2[m][n] = (f32x4)0.f;

    half8 aA[4], aB[4], bA[4], bB[4];

    for (int cc = 0; cc < 4; ++cc) {
        auto ldA1 = [&](int ks, half8* a) {
            #pragma unroll
            for (int m = 0; m < 4; ++m)
                a[m] = *((const half8*)W1F +
                         (size_t)((cc*16 + wave*4 + m)*8 + ks)*64 + lane);
        };
        auto ldA2 = [&](int ks, half8* a) {
            #pragma unroll
            for (int m = 0; m < 4; ++m)
                a[m] = *((const half8*)W2F +
                         (size_t)((wave*4 + m)*32 + cc*8 + ks)*64 + lane);
        };
        auto ldB = [&](const _Float16* src, int ks, half8* bf) {
            #pragma unroll
            for (int n = 0; n < 4; ++n) {
                int byte = (n*16 + lr)*512 + (ks*32 + lhi*8)*2;
                byte ^= (lr & 7) << 4;
                bf[n] = *(const half8*)((const char*)src + byte);
            }
        };
        auto mm = [&](f32x4 (&acc)[4][4], half8* a, half8* bf) {
            #pragma unroll
            for (int m = 0; m < 4; ++m)
                #pragma unroll
                for (int n = 0; n < 4; ++n)
                    acc[m][n] = __builtin_amdgcn_mfma_f32_16x16x32_f16(
                        a[m], bf[n], acc[m][n], 0, 0, 0);
        };

        // ---- GEMM1: acc1 = W1^T-slice x X^T, software-pipelined
        f32x4 acc1[4][4];
        #pragma unroll
        for (int m = 0; m < 4; ++m)
            #pragma unroll
            for (int n = 0; n < 4; ++n) acc1[m][n] = (f32x4)0.f;
        ldA1(0, aA); ldB(xs, 0, bA);
        #pragma unroll
        for (int kp = 0; kp < 4; ++kp) {
            ldA1(2*kp+1, aB); ldB(xs, 2*kp+1, bB);
            mm(acc1, aA, bA);
            if (kp < 3) { ldA1(2*kp+2, aA); ldB(xs, 2*kp+2, bA); }
            mm(acc1, aB, bB);
        }
        // prefetch GEMM2's first A (global, independent of barriers) + b1
        f32x4 b1r[4];
        #pragma unroll
        for (int m = 0; m < 4; ++m)
            b1r[m] = *(const f32x4*)(b1 + cc*256 + wave*64 + m*16 + lhi*4);
        ldA2(0, aA);
        __syncthreads();   // prev chunk's GEMM2 done reading hsT
        // ---- bias + GELU + fp16 -> hsT
        #pragma unroll
        for (int m = 0; m < 4; ++m) {
            #pragma unroll
            for (int n = 0; n < 4; ++n) {
                const int t = n*16 + lr;
                half4v hv;
                hv[0] = (_Float16)gelu_fast(acc1[m][n][0] + b1r[m][0]);
                hv[1] = (_Float16)gelu_fast(acc1[m][n][1] + b1r[m][1]);
                hv[2] = (_Float16)gelu_fast(acc1[m][n][2] + b1r[m][2]);
                hv[3] = (_Float16)gelu_fast(acc1[m][n][3] + b1r[m][3]);
                int byte = t*512 + (wave*64 + m*16 + lhi*4)*2;
                byte ^= (t & 7) << 4;
                *(half4v*)((char*)hsT + byte) = hv;
            }
        }
        __syncthreads();   // hsT ready
        // ---- GEMM2: acc2 += W2^T-slice x H^T, software-pipelined
        ldB(hsT, 0, bA);
        #pragma unroll
        for (int kp = 0; kp < 4; ++kp) {
            ldA2(2*kp+1, aB); ldB(hsT, 2*kp+1, bB);
            mm(acc2, aA, bA);
            if (kp < 3) { ldA2(2*kp+2, aA); ldB(hsT, 2*kp+2, bA); }
            mm(acc2, aB, bB);
        }
    }
    // ---- epilogue: Y^T + b2 + residual -> x
    #pragma unroll
    for (int m = 0; m < 4; ++m) {
        const int c0 = wave*64 + m*16 + lhi*4;
        const f32x4 b2v = *(const f32x4*)(b2 + c0);
        #pragma unroll
        for (int n = 0; n < 4; ++n) {
            const int t = n*16 + lr;
            float* xp = x + (row0 + t)*DIM + c0;
            float4 r = *(const float4*)xp;
            r.x += acc2[m][n][0] + b2v[0];
            r.y += acc2[m][n][1] + b2v[1];
            r.z += acc2[m][n][2] + b2v[2];
            r.w += acc2[m][n][3] + b2v[3];
            *(float4*)xp = r;
        }
    }
}

// ---------------------------------------------------------------------------
// K5: final layernorm
__global__ __launch_bounds__(256) void final_ln_kernel(
        const float* __restrict__ x, const float* __restrict__ g,
        const float* __restrict__ bvec, float* __restrict__ out)
{
    const int tid = threadIdx.x;
    const size_t row = (size_t)blockIdx.x*32 + (tid >> 3);
    const int p = tid & 7;
    const float4* xr = (const float4*)(x + row*DIM);
    float4 v[8];
    float s = 0.f, s2 = 0.f;
    #pragma unroll
    for (int i = 0; i < 8; ++i) {
        v[i] = xr[p + 8*i];
        s  += v[i].x + v[i].y + v[i].z + v[i].w;
        s2 += v[i].x*v[i].x + v[i].y*v[i].y + v[i].z*v[i].z + v[i].w*v[i].w;
    }
    #pragma unroll
    for (int o = 1; o < 8; o <<= 1) { s += __shfl_xor(s, o); s2 += __shfl_xor(s2, o); }
    const float mean = s * (1.f/DIM);
    const float rstd = rsqrtf(s2*(1.f/DIM) - mean*mean + EPS);
    float4* og = (float4*)(out + row*DIM);
    #pragma unroll
    for (int i = 0; i < 8; ++i) {
        const int c4 = (p + 8*i)*4;
        const float4 gg = *(const float4*)&g[c4];
        const float4 bb = *(const float4*)&bvec[c4];
        float4 o_;
        o_.x = (v[i].x - mean)*rstd*gg.x + bb.x;
        o_.y = (v[i].y - mean)*rstd*gg.y + bb.y;
        o_.z = (v[i].z - mean)*rstd*gg.z + bb.z;
        o_.w = (v[i].w - mean)*rstd*gg.w + bb.w;
        og[p + 8*i] = o_;
    }
}

// ---------------------------------------------------------------------------
extern "C" void kernel_launch(void* const* d_in, const int* in_sizes, int n_in,
                              void* d_out, int out_size, void* d_ws, size_t ws_size,
                              hipStream_t stream)
{
    const float* x_in  = (const float*)d_in[0];
    const int*   pidx  = (const int*)d_in[1];
    const int*   scale = (const int*)d_in[3];
    const float* Wq    = (const float*)d_in[4];
    const float* Wk    = (const float*)d_in[5];
    const float* Wv    = (const float*)d_in[6];
    const float* Wo    = (const float*)d_in[7];
    const float* bo    = (const float*)d_in[8];
    const float* ln_g  = (const float*)d_in[9];
    const float* ln_b  = (const float*)d_in[10];
    const float* W1    = (const float*)d_in[11];
    const float* b1    = (const float*)d_in[12];
    const float* W2    = (const float*)d_in[13];
    const float* b2    = (const float*)d_in[14];
    const float* lnf_g = (const float*)d_in[15];
    const float* lnf_b = (const float*)d_in[16];

    float* xbuf = (float*)d_out;                         // x lives in d_out
    float* qk   = (float*)d_ws;                          // B*H*DIM
    float* pxa  = qk + (size_t)B*HEADS*DIM;              // B*CH*H*DIM
    float* pm   = pxa + (size_t)B*CH*HEADS*DIM;          // B*CH*H
    float* ps   = pm + (size_t)B*CH*HEADS;               // B*CH*H
    _Float16* W1F = (_Float16*)(ps + (size_t)B*CH*HEADS);   // DEPTH*DIM*MLPD
    _Float16* W2F = W1F + (size_t)DEPTH*DIM*MLPD;           // DEPTH*MLPD*DIM

    pack_w<<<dim3(MLPD/64, DIM/32, DEPTH), 256, 0, stream>>>(W1, W1F, DIM, MLPD);
    pack_w<<<dim3(DIM/64, MLPD/32, DEPTH), 256, 0, stream>>>(W2, W2F, MLPD, DIM);

    hipMemcpyAsync(xbuf, x_in, (size_t)B*NTOK*DIM*sizeof(float),
                   hipMemcpyDeviceToDevice, stream);

    for (int l = 0; l < DEPTH; ++l) {
        qk2_kernel<<<dim3(4, B), 256, 0, stream>>>(
            xbuf, pidx, scale,
            Wq + (size_t)l*DIM*INNER, Wk + (size_t)l*DIM*INNER, qk);
        attn_pass<<<dim3(CH, B), 256, 0, stream>>>(xbuf, qk, pxa, pm, ps);
        attn_fin<<<B, 256, 0, stream>>>(
            pxa, pm, ps, Wv + (size_t)l*DIM*INNER, Wo + (size_t)l*INNER*DIM,
            bo + (size_t)l*DIM, pidx, scale, xbuf);
        ffn_mfma<<<(B*NTOK)/64, 256, 0, stream>>>(
            xbuf, ln_g + (size_t)l*DIM, ln_b + (size_t)l*DIM,
            W1F + (size_t)l*DIM*MLPD, b1 + (size_t)l*MLPD,
            W2F + (size_t)l*MLPD*DIM, b2 + (size_t)l*DIM);
    }
    final_ln_kernel<<<(B*NTOK)/32, 256, 0, stream>>>(xbuf, lnf_g, lnf_b, xbuf);
}